// Round 1
// baseline (71021.356 us; speedup 1.0000x reference)
//
#include <hip/hip_runtime.h>
#include <math.h>

// Problem dims (fixed by the reference)
#define TT   1024
#define BB   64
#define CIN0 256
#define HH   512
#define Y_ELEMS     (TT * BB * HH)   // 33,554,432
#define STATE_ELEMS (BB * HH)        // 32,768

__device__ __forceinline__ float sigf(float x) {
    return 1.0f / (1.0f + __expf(-x));
}

// One GEMM phase: acc[g] += sum_k V[b,k] * W[g*512+j, k], k in [0,len)
// V: [64, len] row-major. W: [2048, len] row-major. xs: LDS staging [64][68].
__device__ __forceinline__ void gemm_phase(
    const float* __restrict__ V, int len,
    const float* __restrict__ W,
    int j, int b, float acc[4], float* __restrict__ xs)
{
    const int tid = threadIdx.x;
    for (int kb = 0; kb < len; kb += 64) {
        __syncthreads();  // previous chunk's readers done before overwrite
        #pragma unroll
        for (int i = 0; i < 16; ++i) {
            int idx = i * 256 + tid;          // 4096 elements, coalesced in k
            int bb = idx >> 6;
            int kk = idx & 63;
            xs[bb * 68 + kk] = V[(size_t)bb * len + kb + kk];
        }
        __syncthreads();
        const float* __restrict__ xrow = xs + b * 68;
        const float* __restrict__ w0 = W + (size_t)(0 * HH + j) * len + kb;
        const float* __restrict__ w1 = W + (size_t)(1 * HH + j) * len + kb;
        const float* __restrict__ w2 = W + (size_t)(2 * HH + j) * len + kb;
        const float* __restrict__ w3 = W + (size_t)(3 * HH + j) * len + kb;
        #pragma unroll
        for (int kk = 0; kk < 64; kk += 4) {
            float4 xv = *(const float4*)(xrow + kk);   // LDS, 16B
            float4 a0 = *(const float4*)(w0 + kk);     // wave-uniform broadcast
            float4 a1 = *(const float4*)(w1 + kk);
            float4 a2 = *(const float4*)(w2 + kk);
            float4 a3 = *(const float4*)(w3 + kk);
            acc[0] = fmaf(xv.x, a0.x, acc[0]); acc[0] = fmaf(xv.y, a0.y, acc[0]);
            acc[0] = fmaf(xv.z, a0.z, acc[0]); acc[0] = fmaf(xv.w, a0.w, acc[0]);
            acc[1] = fmaf(xv.x, a1.x, acc[1]); acc[1] = fmaf(xv.y, a1.y, acc[1]);
            acc[1] = fmaf(xv.z, a1.z, acc[1]); acc[1] = fmaf(xv.w, a1.w, acc[1]);
            acc[2] = fmaf(xv.x, a2.x, acc[2]); acc[2] = fmaf(xv.y, a2.y, acc[2]);
            acc[2] = fmaf(xv.z, a2.z, acc[2]); acc[2] = fmaf(xv.w, a2.w, acc[2]);
            acc[3] = fmaf(xv.x, a3.x, acc[3]); acc[3] = fmaf(xv.y, a3.y, acc[3]);
            acc[3] = fmaf(xv.z, a3.z, acc[3]); acc[3] = fmaf(xv.w, a3.w, acc[3]);
        }
    }
    __syncthreads();
}

__device__ __forceinline__ void run_layer(
    const float* __restrict__ x, int cin,
    const float* __restrict__ h_in, const float* __restrict__ c_in,
    const float* __restrict__ Wih, const float* __restrict__ Whh,
    const float* __restrict__ bih, const float* __restrict__ bhh,
    float* __restrict__ h_out, float* __restrict__ c_out,
    float* __restrict__ y_out,
    int wg, float* __restrict__ xs)
{
    const int tid = threadIdx.x;
    const int b  = tid & 63;        // batch index
    const int jj = tid >> 6;        // 0..3 (whole wave shares one j -> broadcast W loads)
    const int j  = wg * 4 + jj;     // h column

    float acc[4] = {0.f, 0.f, 0.f, 0.f};
    gemm_phase(x,    cin, Wih, j, b, acc, xs);   // input projection
    gemm_phase(h_in, HH,  Whh, j, b, acc, xs);   // recurrent projection

    // epilogue (PyTorch gate order i, f, g, o)
    float gi = sigf (acc[0] + bih[0 * HH + j] + bhh[0 * HH + j]);
    float gf = sigf (acc[1] + bih[1 * HH + j] + bhh[1 * HH + j]);
    float gg = tanhf(acc[2] + bih[2 * HH + j] + bhh[2 * HH + j]);
    float go = sigf (acc[3] + bih[3 * HH + j] + bhh[3 * HH + j]);

    float c_old = c_in[b * HH + j];
    float c_new = gf * c_old + gi * gg;
    float h_new = go * tanhf(c_new);

    c_out[b * HH + j] = c_new;
    h_out[b * HH + j] = h_new;
    if (y_out) y_out[b * HH + j] = h_new;
}

// Blocks 0..127: layer0 step t. Blocks 128..255: layer1 step t-1 (pipelined).
__global__ __launch_bounds__(256) void lstm_step2(
    const float* __restrict__ x0,
    const float* __restrict__ h0_in, const float* __restrict__ c0_in,
    float* __restrict__ h0_out, float* __restrict__ c0_out,
    const float* __restrict__ Wih0, const float* __restrict__ Whh0,
    const float* __restrict__ bih0, const float* __restrict__ bhh0,
    const float* __restrict__ x1,
    const float* __restrict__ h1_in, const float* __restrict__ c1_in,
    float* __restrict__ h1_out, float* __restrict__ c1_out,
    const float* __restrict__ Wih1, const float* __restrict__ Whh1,
    const float* __restrict__ bih1, const float* __restrict__ bhh1,
    float* __restrict__ y1_out,
    int do_l0, int do_l1)
{
    __shared__ float xs[64 * 68];   // 17.4 KB staging
    int bid = blockIdx.x;
    if (bid < 128) {
        if (!do_l0) return;
        run_layer(x0, CIN0, h0_in, c0_in, Wih0, Whh0, bih0, bhh0,
                  h0_out, c0_out, nullptr, bid, xs);
    } else {
        if (!do_l1) return;
        run_layer(x1, HH, h1_in, c1_in, Wih1, Whh1, bih1, bhh1,
                  h1_out, c1_out, y1_out, bid - 128, xs);
    }
}

extern "C" void kernel_launch(void* const* d_in, const int* in_sizes, int n_in,
                              void* d_out, int out_size, void* d_ws, size_t ws_size,
                              hipStream_t stream) {
    const float* x    = (const float*)d_in[0];
    const float* h0_0 = (const float*)d_in[1];
    const float* c0_0 = (const float*)d_in[2];
    const float* h0_1 = (const float*)d_in[3];
    const float* c0_1 = (const float*)d_in[4];
    const float* Wih0 = (const float*)d_in[5];
    const float* Whh0 = (const float*)d_in[6];
    const float* bih0 = (const float*)d_in[7];
    const float* bhh0 = (const float*)d_in[8];
    const float* Wih1 = (const float*)d_in[9];
    const float* Whh1 = (const float*)d_in[10];
    const float* bih1 = (const float*)d_in[11];
    const float* bhh1 = (const float*)d_in[12];
    float* out = (float*)d_out;

    // ws layout (floats): h0 ping-pong, h1 ping-pong, c0, c1  (786 KB total)
    float* ws     = (float*)d_ws;
    float* h0buf[2] = { ws + 0 * STATE_ELEMS, ws + 1 * STATE_ELEMS };
    float* h1buf[2] = { ws + 2 * STATE_ELEMS, ws + 3 * STATE_ELEMS };
    float* c0buf    = ws + 4 * STATE_ELEMS;
    float* c1buf    = ws + 5 * STATE_ELEMS;

    for (int i = 0; i <= TT; ++i) {
        int t0 = i;       // layer0 timestep
        int t1 = i - 1;   // layer1 timestep (pipelined one launch behind)
        int do_l0 = (t0 < TT);
        int do_l1 = (t1 >= 0);
        int t0c = do_l0 ? t0 : (TT - 1);   // clamp for pointer arithmetic only
        int t1c = do_l1 ? t1 : 0;

        const float* x0p   = x + (size_t)t0c * BB * CIN0;
        const float* h0inp = (t0c == 0) ? h0_0 : h0buf[t0c & 1];
        const float* c0inp = (t0c == 0) ? c0_0 : c0buf;
        float*       h0out = h0buf[(t0c + 1) & 1];

        const float* x1p   = h0buf[(t1c + 1) & 1];   // y0[t1] = h0 state after step t1
        const float* h1inp = (t1c == 0) ? h0_1 : h1buf[t1c & 1];
        const float* c1inp = (t1c == 0) ? c0_1 : c1buf;
        float*       h1out = h1buf[(t1c + 1) & 1];
        float*       y1o   = out + (size_t)t1c * BB * HH;

        lstm_step2<<<256, 256, 0, stream>>>(
            x0p, h0inp, c0inp, h0out, c0buf, Wih0, Whh0, bih0, bhh0,
            x1p, h1inp, c1inp, h1out, c1buf, Wih1, Whh1, bih1, bhh1,
            y1o, do_l0, do_l1);
    }

    // Final states: h0 final is in h0buf[0] (t=1023 -> out buf (1024)&1=0),
    // h1 final in h1buf[0]. Return order: y1, h1f, c1f, h2f, c2f.
    size_t sb = STATE_ELEMS * sizeof(float);
    hipMemcpyAsync(out + Y_ELEMS + 0 * STATE_ELEMS, h0buf[0], sb, hipMemcpyDeviceToDevice, stream);
    hipMemcpyAsync(out + Y_ELEMS + 1 * STATE_ELEMS, c0buf,    sb, hipMemcpyDeviceToDevice, stream);
    hipMemcpyAsync(out + Y_ELEMS + 2 * STATE_ELEMS, h1buf[0], sb, hipMemcpyDeviceToDevice, stream);
    hipMemcpyAsync(out + Y_ELEMS + 3 * STATE_ELEMS, c1buf,    sb, hipMemcpyDeviceToDevice, stream);
}

// Round 2
// 22041.161 us; speedup vs baseline: 3.2222x; 3.2222x over previous
//
#include <hip/hip_runtime.h>

// ---------------------------------------------------------------------------
// Persistent weight-stationary LSTM, bf16 MFMA, hand-rolled grid barrier.
// T=1024 B=64 C=256 H=512, 2 layers, fp32 in/out.
//  - 256 blocks x 256 threads, 1 block/CU, co-resident; blocks 0..127 = layer0
//    (step t), 128..255 = layer1 (step t-1) -> one grid barrier per tick.
//  - Weights bf16, packed once into MFMA B-frag order, held in VGPRs all run.
//  - h state stored bf16 (written by epilogue), c state lives in a register.
//  - mfma_f32_16x16x32_bf16: A[m=lane&15][k=quad*8+j], B(N,K)[n=lane&15][k=quad*8+j],
//    D[m=quad*4+reg][n=lane&15]  (guide-verified mapping, m90/m97 convention)
// ---------------------------------------------------------------------------

#define TT 1024
#define BB 64
#define CC 256
#define HH 512
#define Y_ELEMS (TT * BB * HH)
#define S_ELEMS (BB * HH)

typedef __attribute__((ext_vector_type(8))) short bf16x8;
typedef __attribute__((ext_vector_type(4))) float f32x4;
typedef unsigned int u32;
typedef unsigned short u16;

// ---- ws layout (bytes) ----
#define WS_BAR 0           // 1024 u32 (barrier lines, 128B-spread)
#define WS_BSUM0 4096      // 2048 f32
#define WS_BSUM1 12288     // 2048 f32
#define WS_H0 20480        // 2 * 32768 u16 (h0 ping-pong, bf16)
#define WS_H1 151552       // 2 * 32768 u16
#define WS_WPK0 282624     // 128*24*64*8 bf16  (layer0 packed W)
#define WS_WPK1 3428352    // 128*32*64*8 bf16  (layer1 packed W)
// end ~ 7.62 MB

__device__ __forceinline__ u16 f2b_rne(float f) {
    u32 u = __float_as_uint(f);
    return (u16)((u + 0x7FFFu + ((u >> 16) & 1u)) >> 16);
}
__device__ __forceinline__ u16 f2b_fast(float f) {  // round-half-up, 2 ops
    return (u16)((__float_as_uint(f) + 0x8000u) >> 16);
}
__device__ __forceinline__ float sigf(float z) { return 1.0f / (1.0f + __expf(-z)); }
__device__ __forceinline__ float tanh_f(float z) { return 2.0f / (1.0f + __expf(-2.0f * z)) - 1.0f; }

__device__ __forceinline__ bf16x8 pack8(float4 a, float4 b) {
    union { u16 u[8]; bf16x8 v; } r;
    r.u[0] = f2b_fast(a.x); r.u[1] = f2b_fast(a.y); r.u[2] = f2b_fast(a.z); r.u[3] = f2b_fast(a.w);
    r.u[4] = f2b_fast(b.x); r.u[5] = f2b_fast(b.y); r.u[6] = f2b_fast(b.z); r.u[7] = f2b_fast(b.w);
    return r.v;
}

// Two-level grid barrier: 16 groups of 16 blocks -> root -> gen broadcast.
// Data visibility: __syncthreads drains vmcnt (all waves' stores in L2);
// __threadfence (agent) writes back L2; readers' acquire-load invalidates.
__device__ __forceinline__ void grid_barrier(u32* bar, u32 target) {
    __syncthreads();
    if (threadIdx.x == 0) {
        __threadfence();
        u32 g = (u32)blockIdx.x >> 4;
        u32 prev = __hip_atomic_fetch_add(&bar[g * 32], 1u, __ATOMIC_ACQ_REL, __HIP_MEMORY_SCOPE_AGENT);
        if (prev == 15u) {
            u32 p2 = __hip_atomic_fetch_add(&bar[512], 1u, __ATOMIC_ACQ_REL, __HIP_MEMORY_SCOPE_AGENT);
            if (p2 == 15u) {
                #pragma unroll
                for (int k = 0; k < 16; ++k)
                    __hip_atomic_store(&bar[k * 32], 0u, __ATOMIC_RELAXED, __HIP_MEMORY_SCOPE_AGENT);
                __hip_atomic_store(&bar[512], 0u, __ATOMIC_RELAXED, __HIP_MEMORY_SCOPE_AGENT);
                __hip_atomic_fetch_add(&bar[544], 1u, __ATOMIC_RELEASE, __HIP_MEMORY_SCOPE_AGENT);
            }
        }
        while (__hip_atomic_load(&bar[544], __ATOMIC_RELAXED, __HIP_MEMORY_SCOPE_AGENT) < target)
            __builtin_amdgcn_s_sleep(2);
        (void)__hip_atomic_load(&bar[544], __ATOMIC_ACQUIRE, __HIP_MEMORY_SCOPE_AGENT);
    }
    __syncthreads();
}

// ---- init: zero barrier, bsum = bih+bhh, h buffers <- bf16(initial h) ----
__global__ void k_init(const float* __restrict__ bih0, const float* __restrict__ bhh0,
                       const float* __restrict__ bih1, const float* __restrict__ bhh1,
                       const float* __restrict__ h00, const float* __restrict__ h01,
                       unsigned char* __restrict__ ws) {
    u32* bar = (u32*)(ws + WS_BAR);
    float* bs0 = (float*)(ws + WS_BSUM0);
    float* bs1 = (float*)(ws + WS_BSUM1);
    u16* h0 = (u16*)(ws + WS_H0);
    u16* h1 = (u16*)(ws + WS_H1);
    int t = blockIdx.x * 256 + threadIdx.x;  // 32768 threads
    if (t < 1024) bar[t] = 0u;
    if (t < 2048) { bs0[t] = bih0[t] + bhh0[t]; bs1[t] = bih1[t] + bhh1[t]; }
    if (t < S_ELEMS) { h0[t] = f2b_rne(h00[t]); h1[t] = f2b_rne(h01[t]); }
}

// ---- weight pack: fp32 [4H,K] -> bf16 B-frag order wpk[bidL][kt][lane][8] ----
// rows permuted: n-index (lane&15) = gg*4+jj  <->  W row = gg*512 + bidL*4 + jj
__global__ void k_wprep(const float* __restrict__ Wih0, const float* __restrict__ Whh0,
                        const float* __restrict__ Wih1, const float* __restrict__ Whh1,
                        unsigned char* __restrict__ ws) {
    u16* wpk0 = (u16*)(ws + WS_WPK0);
    u16* wpk1 = (u16*)(ws + WS_WPK1);
    int u = blockIdx.x * 256 + threadIdx.x;  // 458752 threads
    const float* s;
    u16* d;
    if (u < 128 * 24 * 64) {  // layer0: 8 x-tiles (K=256) + 16 h-tiles (K=512)
        int bidL = u / (24 * 64);
        int kt = (u >> 6) % 24;
        int lane = u & 63;
        int n = lane & 15, quad = lane >> 4;
        int row = (n >> 2) * 512 + bidL * 4 + (n & 3);
        int k = kt * 32 + quad * 8;
        s = (k < 256) ? (Wih0 + (size_t)row * 256 + k) : (Whh0 + (size_t)row * 512 + (k - 256));
        d = wpk0 + (size_t)((bidL * 24 + kt) * 64 + lane) * 8;
    } else {  // layer1: 16 y0-tiles + 16 h1-tiles (K=1024)
        int v = u - 128 * 24 * 64;
        int bidL = v / (32 * 64);
        int kt = (v >> 6) % 32;
        int lane = v & 63;
        int n = lane & 15, quad = lane >> 4;
        int row = (n >> 2) * 512 + bidL * 4 + (n & 3);
        int k = kt * 32 + quad * 8;
        s = (k < 512) ? (Wih1 + (size_t)row * 512 + k) : (Whh1 + (size_t)row * 512 + (k - 512));
        d = wpk1 + (size_t)((bidL * 32 + kt) * 64 + lane) * 8;
    }
    #pragma unroll
    for (int i = 0; i < 8; ++i) d[i] = f2b_rne(s[i]);
}

// ---- the persistent tick loop, templated on layer ----
template <int LAYER>
__device__ void run_ticks(const float* __restrict__ x, const float* __restrict__ c0,
                          float* __restrict__ out, unsigned char* __restrict__ ws, int bidL) {
    constexpr int NKT = (LAYER == 0) ? 24 : 32;
    u32* bar = (u32*)(ws + WS_BAR);
    const float* bs = (const float*)(ws + (LAYER == 0 ? WS_BSUM0 : WS_BSUM1));
    u16* h0b[2] = { (u16*)(ws + WS_H0), (u16*)(ws + WS_H0) + S_ELEMS };
    u16* h1b[2] = { (u16*)(ws + WS_H1), (u16*)(ws + WS_H1) + S_ELEMS };
    const u16* wpk = (const u16*)(ws + (LAYER == 0 ? WS_WPK0 : WS_WPK1));

    const int tid = threadIdx.x, lane = tid & 63, wave = tid >> 6;
    const int r16 = lane & 15, quad = lane >> 4, q8 = quad * 8;
    const int gg = r16 >> 2, jj = r16 & 3;
    const int b0 = wave * 16;
    const int col = bidL * 4 + jj;            // h column this lane finalizes
    const int myb = b0 + quad * 4 + gg;       // batch this lane finalizes
    const int sl0 = (quad << 4) | (0 << 2) | jj;
    const int sl1 = (quad << 4) | (1 << 2) | jj;
    const int sl2 = (quad << 4) | (2 << 2) | jj;
    const int sl3 = (quad << 4) | (3 << 2) | jj;

    // biases (hoisted), c state in register for the whole run
    const float bi = bs[0 * HH + col], bf_ = bs[1 * HH + col];
    const float bg = bs[2 * HH + col], bo = bs[3 * HH + col];
    float c = c0[myb * HH + col];

    // weight fragments: resident in VGPRs for all 1025 ticks
    bf16x8 w[NKT];
    {
        const u16* wp = wpk + (size_t)(bidL * NKT * 64 + lane) * 8;
        #pragma unroll
        for (int kt = 0; kt < NKT; ++kt) w[kt] = *(const bf16x8*)(wp + (size_t)kt * 64 * 8);
    }

    for (int i = 0; i <= TT; ++i) {
        const bool active = (LAYER == 0) ? (i < TT) : (i >= 1);
        const int t = (LAYER == 0) ? i : i - 1;
        if (active) {
            f32x4 aE = {0.f, 0.f, 0.f, 0.f}, aO = {0.f, 0.f, 0.f, 0.f};
            if (LAYER == 0) {
                // x projection: fp32 -> bf16 (half-up) in flight
                const float* xp = x + ((size_t)t * BB + b0 + r16) * CC + q8;
                #pragma unroll
                for (int kt = 0; kt < 8; ++kt) {
                    float4 f0 = *(const float4*)(xp + kt * 32);
                    float4 f1 = *(const float4*)(xp + kt * 32 + 4);
                    bf16x8 a = pack8(f0, f1);
                    if (kt & 1) aO = __builtin_amdgcn_mfma_f32_16x16x32_bf16(a, w[kt], aO, 0, 0, 0);
                    else        aE = __builtin_amdgcn_mfma_f32_16x16x32_bf16(a, w[kt], aE, 0, 0, 0);
                }
                // recurrent: h0 (bf16) at buf parity t&1
                const u16* hp = h0b[t & 1] + (size_t)(b0 + r16) * HH + q8;
                #pragma unroll
                for (int kt = 0; kt < 16; ++kt) {
                    bf16x8 a = *(const bf16x8*)(hp + kt * 32);
                    if (kt & 1) aO = __builtin_amdgcn_mfma_f32_16x16x32_bf16(a, w[8 + kt], aO, 0, 0, 0);
                    else        aE = __builtin_amdgcn_mfma_f32_16x16x32_bf16(a, w[8 + kt], aE, 0, 0, 0);
                }
            } else {
                // y0[t] = h0 written at tick t (parity (t+1)&1); h1 prev at t&1
                const u16* pa = h0b[(t + 1) & 1] + (size_t)(b0 + r16) * HH + q8;
                const u16* pb = h1b[t & 1] + (size_t)(b0 + r16) * HH + q8;
                #pragma unroll
                for (int kt = 0; kt < 16; ++kt) {
                    bf16x8 a = *(const bf16x8*)(pa + kt * 32);
                    if (kt & 1) aO = __builtin_amdgcn_mfma_f32_16x16x32_bf16(a, w[kt], aO, 0, 0, 0);
                    else        aE = __builtin_amdgcn_mfma_f32_16x16x32_bf16(a, w[kt], aE, 0, 0, 0);
                }
                #pragma unroll
                for (int kt = 0; kt < 16; ++kt) {
                    bf16x8 a = *(const bf16x8*)(pb + kt * 32);
                    if (kt & 1) aO = __builtin_amdgcn_mfma_f32_16x16x32_bf16(a, w[16 + kt], aO, 0, 0, 0);
                    else        aE = __builtin_amdgcn_mfma_f32_16x16x32_bf16(a, w[16 + kt], aE, 0, 0, 0);
                }
            }
            f32x4 acc = aE + aO;

            // gather the 4 gates for (myb, col): lanes sharing (quad,jj), gg = gate
            float gi = 0.f, gf = 0.f, gc = 0.f, go = 0.f;
            #pragma unroll
            for (int r = 0; r < 4; ++r) {
                float v0 = __shfl(acc[r], sl0, 64);
                float v1 = __shfl(acc[r], sl1, 64);
                float v2 = __shfl(acc[r], sl2, 64);
                float v3 = __shfl(acc[r], sl3, 64);
                if (r == gg) { gi = v0; gf = v1; gc = v2; go = v3; }
            }
            gi = sigf(gi + bi);
            gf = sigf(gf + bf_);
            gc = tanh_f(gc + bg);
            go = sigf(go + bo);
            c = gf * c + gi * gc;
            float h = go * tanh_f(c);

            u16* hw = (LAYER == 0) ? h0b[(t + 1) & 1] : h1b[(t + 1) & 1];
            hw[myb * HH + col] = f2b_rne(h);
            if (LAYER == 1) out[(size_t)t * S_ELEMS + myb * HH + col] = h;
            if (t == TT - 1) {
                float* fin = out + Y_ELEMS + (LAYER == 0 ? 0 : 2) * S_ELEMS;
                fin[myb * HH + col] = h;
                fin[S_ELEMS + myb * HH + col] = c;
            }
        }
        grid_barrier(bar, (u32)(i + 1));
    }
}

__global__ __launch_bounds__(256) void k_lstm(const float* __restrict__ x,
                                              const float* __restrict__ c00,
                                              const float* __restrict__ c01,
                                              float* __restrict__ out,
                                              unsigned char* __restrict__ ws) {
    const int bid = blockIdx.x;
    if (bid < 128) run_ticks<0>(x, c00, out, ws, bid);
    else           run_ticks<1>(x, c01, out, ws, bid - 128);
}

extern "C" void kernel_launch(void* const* d_in, const int* in_sizes, int n_in,
                              void* d_out, int out_size, void* d_ws, size_t ws_size,
                              hipStream_t stream) {
    const float* x    = (const float*)d_in[0];
    const float* h0_0 = (const float*)d_in[1];
    const float* c0_0 = (const float*)d_in[2];
    const float* h0_1 = (const float*)d_in[3];
    const float* c0_1 = (const float*)d_in[4];
    const float* Wih0 = (const float*)d_in[5];
    const float* Whh0 = (const float*)d_in[6];
    const float* bih0 = (const float*)d_in[7];
    const float* bhh0 = (const float*)d_in[8];
    const float* Wih1 = (const float*)d_in[9];
    const float* Whh1 = (const float*)d_in[10];
    const float* bih1 = (const float*)d_in[11];
    const float* bhh1 = (const float*)d_in[12];
    float* out = (float*)d_out;
    unsigned char* ws = (unsigned char*)d_ws;

    k_init<<<128, 256, 0, stream>>>(bih0, bhh0, bih1, bhh1, h0_0, h0_1, ws);
    k_wprep<<<1792, 256, 0, stream>>>(Wih0, Whh0, Wih1, Whh1, ws);
    k_lstm<<<256, 256, 0, stream>>>(x, c0_0, c0_1, out, ws);
}